// Round 12
// baseline (383.642 us; speedup 1.0000x reference)
//
#include <hip/hip_runtime.h>

#define B_   8
#define S_   2048
#define H_   768
#define K_   128
#define C_   256
#define SH_  2052              // S + 4 halo rows (2 each side)
#define MTOK (B_*S_)           // 16384 tokens

typedef __attribute__((ext_vector_type(8))) short short8;
typedef __attribute__((ext_vector_type(4))) float f32x4;

typedef __attribute__((address_space(1))) const void gvoid;
typedef __attribute__((address_space(3))) void lvoid;

__device__ __forceinline__ void gload16(const void* g, void* l) {
    __builtin_amdgcn_global_load_lds((gvoid*)g, (lvoid*)l, 16, 0, 0);
}

__device__ __forceinline__ ushort f2b(float f) {
    union { float f; unsigned u; } v; v.f = f;
    unsigned r = v.u + 0x7fffu + ((v.u >> 16) & 1u);   // RNE
    return (ushort)(r >> 16);
}
__device__ __forceinline__ float b2f(ushort u) {
    union { unsigned u; float f; } v; v.u = ((unsigned)u) << 16;
    return v.f;
}
__device__ __forceinline__ float fast_tanh(float x) {
    float e = __expf(2.f * x);
    return 1.f - 2.f / (e + 1.f);
}

// ---------------- k_prep: maxlen + halo-zero + build_xh + weight cvts + Wc zero --------

struct CvtE { const float* src; ushort* dst; int n; int kh; int sld; };  // kh<0: zero-fill

struct PrepP {
    const float* mask; int* Lp; ushort* lh;     // y=0, bx=0
    const float* rep;  ushort* xh;              // y=0, bx>0
    CvtE e[12];                                 // y=1..12
};

__global__ __launch_bounds__(256) void k_prep(PrepP p) {
    const int tid = threadIdx.x;
    const int y = blockIdx.y;
    if (y == 0) {
        if (blockIdx.x == 0) {
            __shared__ float sh[4];
            float mx = 0.f;
            for (int b = 0; b < B_; ++b) {
                float s = 0.f;
                for (int q = tid; q < 512; q += 256) {
                    const float4 v = ((const float4*)(p.mask + b * S_))[q];
                    s += v.x + v.y + v.z + v.w;
                }
#pragma unroll
                for (int off = 32; off; off >>= 1) s += __shfl_xor(s, off);
                if ((tid & 63) == 0) sh[tid >> 6] = s;
                __syncthreads();
                if (tid == 0) mx = fmaxf(mx, sh[0] + sh[1] + sh[2] + sh[3]);
                __syncthreads();
            }
            if (tid == 0) *p.Lp = (int)mx;
            for (int i = tid; i < B_ * 4 * K_; i += 256) {
                const int b = i >> 9;
                const int rc = i & 511;
                const int rr = rc >> 7;
                const int cc = rc & 127;
                const int row = (rr < 2) ? rr : (2048 + rr);
                p.lh[((size_t)b * SH_ + row) * K_ + cc] = 0;
            }
        } else {
            int i = (blockIdx.x - 1) * 256 + tid;
            const int stride = (gridDim.x - 1) * 256;
            const int n4 = B_ * SH_ * H_ / 4;
            for (; i < n4; i += stride) {
                const int idx = i * 4;
                const int h = idx % H_;
                const int rs = idx / H_;
                const int s = rs % SH_;
                const int b = rs / SH_;
                ushort4 o; o.x = 0; o.y = 0; o.z = 0; o.w = 0;
                if (s >= 2 && s < S_ + 2) {
                    const float4 v = *(const float4*)(p.rep + ((size_t)b * S_ + (s - 2)) * H_ + h);
                    o.x = f2b(v.x); o.y = f2b(v.y); o.z = f2b(v.z); o.w = f2b(v.w);
                }
                *(ushort4*)(p.xh + idx) = o;
            }
        }
    } else {
        const CvtE e = p.e[y - 1];
        int i = blockIdx.x * 256 + tid;
        const int stride = gridDim.x * 256;
        for (; i < e.n; i += stride) {
            if (e.kh < 0) {
                e.dst[i] = 0;
            } else if (e.kh) {
                const int c = i / e.kh;
                const int r = i - c * e.kh;
                e.dst[i] = f2b(e.src[r * e.sld + c]);
            } else {
                e.dst[i] = f2b(e.src[i]);
            }
        }
    }
}

// ---- k_compw: composite decoder weights into combined Wc[768][640] ----

struct CompE { const ushort* w; int wld; int woff; ushort* o; int old_; int koff; };
struct CompP { const ushort* dtrT; CompE e[9]; };

__global__ __launch_bounds__(256) void k_compw(CompP p) {
    __shared__ __align__(16) ushort As[128 * 64];
    __shared__ __align__(16) ushort Bs[128 * 64];
    const CompE e = p.e[blockIdx.y];
    const int tid = threadIdx.x;
    const int w = tid >> 6, lane = tid & 63;
    const int l15 = lane & 15, lk = lane >> 4;
    const int wr = w >> 1, wc = w & 1;
    const int n_base = blockIdx.x * 128;
    f32x4 acc[4][4] = {};
    const int srow = lane >> 3;
    const int scol = (lane & 7) * 8;

    for (int kt = 0; kt < 12; ++kt) {
        const int kk = kt << 6;
#pragma unroll
        for (int q = 0; q < 4; ++q) {
            const int r = w * 32 + q * 8;
            gload16(p.dtrT + (size_t)(r + srow) * 768 + kk + scol, As + r * 64);
            gload16(e.w + (size_t)(n_base + r + srow) * e.wld + e.woff + kk + scol, Bs + r * 64);
        }
        __syncthreads();
#pragma unroll
        for (int ks = 0; ks < 2; ++ks) {
            short8 af[4], bfr[4];
#pragma unroll
            for (int i = 0; i < 4; ++i)
                af[i] = *(const short8*)(As + (wr * 64 + i * 16 + l15) * 64 + ks * 32 + 8 * lk);
#pragma unroll
            for (int j = 0; j < 4; ++j)
                bfr[j] = *(const short8*)(Bs + (wc * 64 + j * 16 + l15) * 64 + ks * 32 + 8 * lk);
#pragma unroll
            for (int i = 0; i < 4; ++i)
#pragma unroll
                for (int j = 0; j < 4; ++j)
                    acc[i][j] = __builtin_amdgcn_mfma_f32_16x16x32_bf16(af[i], bfr[j], acc[i][j], 0, 0, 0);
        }
        __syncthreads();
    }
#pragma unroll
    for (int i = 0; i < 4; ++i)
#pragma unroll
        for (int j = 0; j < 4; ++j)
#pragma unroll
            for (int jj = 0; jj < 4; ++jj) {
                const int jr = wr * 64 + i * 16 + 4 * lk + jj;
                const int c  = n_base + wc * 64 + j * 16 + l15;
                e.o[(size_t)c * e.old_ + e.koff + jr] = f2b(acc[i][j][jj]);
            }
}

// ---------------- g3b: enc conv GEMM, BM=64 BN=256 BK=64, 2-deep, 2 blocks/CU ----------
// 256 thr (4 waves 1x4, wave tile 64x64). Grid 768: idx<256 k5, <512 k3, else k1.
// g4-proven schedule: counted vmcnt(10); stage(t+2) after barrier2 into drained buffer.

struct G3P {
    const ushort* A;
    const ushort* W0;   // k=1 weights [256][768]
    const ushort* W1;   // k=3 [256][2304]
    const ushort* W2;   // k=5 [256][3840]
    int lda;
    ushort* outB; int ldoB;
};

__global__ __launch_bounds__(256, 2) void g3b(G3P p) {
    constexpr int TPT = 12;                  // K-tiles per tap
    constexpr int LDA = 768;
    constexpr int ASEG = 512;                // 64 rows x 8 segs
    constexpr int BSEG = 2048;               // 256 rows x 8 segs
    __shared__ __align__(16) ushort lds[2][(ASEG + BSEG) * 8];   // 80 KB

    const int tid = threadIdx.x;
    const int wc = tid >> 6, lane = tid & 63;
    const int l15 = lane & 15, lk = lane >> 4;
    const int axor = l15 & 7;

    int idx = blockIdx.x;
    int br;
    if (idx < 256) br = 2;                         // k=5 first (long pole)
    else if (idx < 512) { br = 1; idx -= 256; }
    else { br = 0; idx -= 512; }
    const int m_base = idx * 64;
    const int n_base = br * 256;
    const int nt = TPT * (2 * br + 1);
    const int Ktot = LDA * (2 * br + 1);
    const ushort* Wt = (br == 0) ? p.W0 : (br == 1) ? p.W1 : p.W2;
    const int arow0 = m_base + ((m_base >> 11) << 2) + (2 - br);   // halo'd row base

    auto stage = [&](int kt, int bufi) {
        const int tap = kt / TPT;
        const int h0 = (kt - tap * TPT) << 6;
        ushort* Ab = &lds[bufi][0];
        ushort* Bb = &lds[bufi][ASEG * 8];
#pragma unroll
        for (int q = 0; q < 2; ++q) {
            const int seg = q * 256 + tid;
            const int row = seg >> 3;
            const int s = (seg & 7) ^ (row & 7);
            gload16(p.A + (size_t)(arow0 + tap + row) * LDA + h0 + s * 8, Ab + seg * 8);
        }
#pragma unroll
        for (int q = 0; q < 8; ++q) {
            const int seg = q * 256 + tid;
            const int row = seg >> 3;
            const int s = (seg & 7) ^ (row & 7);
            gload16(Wt + (size_t)row * Ktot + (kt << 6) + s * 8, Bb + seg * 8);
        }
    };

    f32x4 acc[4][4] = {};

    stage(0, 0);
    stage(1, 1);

    for (int t = 0; t < nt; ++t) {
        const int cur = t & 1;
        const ushort* Ab = &lds[cur][0];
        const ushort* Bb = &lds[cur][ASEG * 8];
        if (t + 1 < nt) asm volatile("s_waitcnt vmcnt(10)" ::: "memory");
        else            asm volatile("s_waitcnt vmcnt(0)" ::: "memory");
        __builtin_amdgcn_sched_barrier(0);
        asm volatile("s_barrier" ::: "memory");     // tile t resident for all waves
        __builtin_amdgcn_sched_barrier(0);

        short8 af[4][2], bf[4][2];
#pragma unroll
        for (int mi = 0; mi < 4; ++mi)
#pragma unroll
            for (int ks = 0; ks < 2; ++ks)
                af[mi][ks] = *(const short8*)(Ab + (mi * 16 + l15) * 64 + ((((ks << 2) | lk) ^ axor) << 3));
#pragma unroll
        for (int ni = 0; ni < 4; ++ni)
#pragma unroll
            for (int ks = 0; ks < 2; ++ks)
                bf[ni][ks] = *(const short8*)(Bb + (wc * 64 + ni * 16 + l15) * 64 + ((((ks << 2) | lk) ^ axor) << 3));
        asm volatile("s_waitcnt lgkmcnt(0)" ::: "memory");
        __builtin_amdgcn_sched_barrier(0);
        asm volatile("s_barrier" ::: "memory");     // all waves done reading buf[cur]
        __builtin_amdgcn_sched_barrier(0);
        if (t + 2 < nt) stage(t + 2, cur);          // overwrite drained buffer under MFMA
        __builtin_amdgcn_sched_barrier(0);
        __builtin_amdgcn_s_setprio(1);
#pragma unroll
        for (int mi = 0; mi < 4; ++mi)
#pragma unroll
            for (int ni = 0; ni < 4; ++ni) {
                acc[mi][ni] = __builtin_amdgcn_mfma_f32_16x16x32_bf16(af[mi][0], bf[ni][0], acc[mi][ni], 0, 0, 0);
                acc[mi][ni] = __builtin_amdgcn_mfma_f32_16x16x32_bf16(af[mi][1], bf[ni][1], acc[mi][ni], 0, 0, 0);
            }
        __builtin_amdgcn_s_setprio(0);
        __builtin_amdgcn_sched_barrier(0);
    }

#pragma unroll
    for (int mi = 0; mi < 4; ++mi)
#pragma unroll
        for (int ni = 0; ni < 4; ++ni)
#pragma unroll
            for (int jj = 0; jj < 4; ++jj) {
                const int r = m_base + mi * 16 + 4 * lk + jj;
                const int n = n_base + wc * 64 + ni * 16 + l15;
                p.outB[(size_t)r * p.ldoB + n] = f2b(acc[mi][ni][jj]);
            }
}

// ---------------- g4: 4-wave, BM=128 BN=192, 2-deep ring, 2 blocks/CU ------------------

struct G4P {
    const ushort* A;
    const ushort* W;
    int Ktot;
    int lda;
    ushort* outB; int ldoB;
    float*  outF; int ldoF;
    int act;
    int haloA;
};

__global__ __launch_bounds__(256, 2) void g4(G4P p) {
    constexpr int ASEG = 1024;   // 128 rows x 8
    constexpr int BSEG = 1536;   // 192 rows x 8
    __shared__ __align__(16) ushort lds[2][(ASEG + BSEG) * 8];   // 80 KB total

    const int tid = threadIdx.x;
    const int w = tid >> 6, lane = tid & 63;
    const int l15 = lane & 15, lk = lane >> 4;
    const int wr = w >> 1, wc = w & 1;
    const int axor = l15 & 7;
    const int m_base = blockIdx.x * 128;
    const int n_base = blockIdx.y * 192;
    const int nt = p.Ktot >> 6;
    const int abase = p.haloA ? (m_base + ((m_base >> 11) << 2)) : m_base;

    auto stage = [&](int kt, int bufi) {
        const int kk = kt << 6;
        ushort* Ab = &lds[bufi][0];
        ushort* Bb = &lds[bufi][ASEG * 8];
#pragma unroll
        for (int q = 0; q < 4; ++q) {
            const int seg = q * 256 + tid;
            const int row = seg >> 3;
            const int s = (seg & 7) ^ (row & 7);
            gload16(p.A + (size_t)(abase + row) * p.lda + kk + s * 8, Ab + seg * 8);
        }
#pragma unroll
        for (int q = 0; q < 6; ++q) {
            const int seg = q * 256 + tid;
            const int row = seg >> 3;
            const int s = (seg & 7) ^ (row & 7);
            gload16(p.W + (size_t)(n_base + row) * p.Ktot + kk + s * 8, Bb + seg * 8);
        }
    };

    f32x4 acc[4][6] = {};

    stage(0, 0);
    stage(1, 1);

    for (int t = 0; t < nt; ++t) {
        const int cur = t & 1;
        const ushort* Ab = &lds[cur][0];
        const ushort* Bb = &lds[cur][ASEG * 8];
        if (t + 1 < nt) asm volatile("s_waitcnt vmcnt(10)" ::: "memory");
        else            asm volatile("s_waitcnt vmcnt(0)" ::: "memory");
        __builtin_amdgcn_sched_barrier(0);
        asm volatile("s_barrier" ::: "memory");
        __builtin_amdgcn_sched_barrier(0);

        short8 af[4][2], bf[6][2];
#pragma unroll
        for (int mi = 0; mi < 4; ++mi)
#pragma unroll
            for (int ks = 0; ks < 2; ++ks)
                af[mi][ks] = *(const short8*)(Ab + (wr * 64 + mi * 16 + l15) * 64 + ((((ks << 2) | lk) ^ axor) << 3));
#pragma unroll
        for (int ni = 0; ni < 6; ++ni)
#pragma unroll
            for (int ks = 0; ks < 2; ++ks)
                bf[ni][ks] = *(const short8*)(Bb + (wc * 96 + ni * 16 + l15) * 64 + ((((ks << 2) | lk) ^ axor) << 3));
        asm volatile("s_waitcnt lgkmcnt(0)" ::: "memory");
        __builtin_amdgcn_sched_barrier(0);
        asm volatile("s_barrier" ::: "memory");
        __builtin_amdgcn_sched_barrier(0);
        if (t + 2 < nt) stage(t + 2, cur);
        __builtin_amdgcn_sched_barrier(0);
        __builtin_amdgcn_s_setprio(1);
#pragma unroll
        for (int mi = 0; mi < 4; ++mi)
#pragma unroll
            for (int ni = 0; ni < 6; ++ni) {
                acc[mi][ni] = __builtin_amdgcn_mfma_f32_16x16x32_bf16(af[mi][0], bf[ni][0], acc[mi][ni], 0, 0, 0);
                acc[mi][ni] = __builtin_amdgcn_mfma_f32_16x16x32_bf16(af[mi][1], bf[ni][1], acc[mi][ni], 0, 0, 0);
            }
        __builtin_amdgcn_s_setprio(0);
        __builtin_amdgcn_sched_barrier(0);
    }

#pragma unroll
    for (int mi = 0; mi < 4; ++mi)
#pragma unroll
        for (int ni = 0; ni < 6; ++ni)
#pragma unroll
            for (int jj = 0; jj < 4; ++jj) {
                const int r = m_base + wr * 64 + mi * 16 + 4 * lk + jj;
                const int n = n_base + wc * 96 + ni * 16 + l15;
                float v = acc[mi][ni][jj];
                if (p.act) v = fast_tanh(v);
                if (p.outF) p.outF[(size_t)r * p.ldoF + n] = v;
                if (p.outB) p.outB[(size_t)r * p.ldoB + n] = f2b(v);
            }
}

// ------- gemm_loc: location GEMM (BM=64, BN=128, 2-phase) + fused row-normalize --------

struct GLP {
    const ushort* A;      // h2 [MTOK][768]
    const ushort* Wt;     // enc_tr [128][768]
    float* outF;          // location f32 [MTOK][128]
    ushort* outH;         // halo'd location bf16 [B][SH][128]
    ushort* outN;         // normed bf16 [MTOK][128]
};

__global__ __launch_bounds__(256) void gemm_loc(GLP p) {
    __shared__ __align__(16) ushort As[64 * 64];
    __shared__ __align__(16) ushort Bs[128 * 64];
    __shared__ float rowss[64][2];
    const int tid = threadIdx.x;
    const int w = tid >> 6, lane = tid & 63;
    const int l15 = lane & 15, lk = lane >> 4;
    const int m_base = blockIdx.x * 64;
    const int wr = w >> 1, wc = w & 1;
    f32x4 acc[2][4] = {};
    const int srow = lane >> 3;
    const int scol = (lane & 7) * 8;

    for (int kt = 0; kt < 12; ++kt) {
        const int kk = kt << 6;
#pragma unroll
        for (int q = 0; q < 2; ++q) {
            const int r = w * 16 + q * 8;
            gload16(p.A + (size_t)(m_base + r + srow) * H_ + kk + scol, As + r * 64);
        }
#pragma unroll
        for (int q = 0; q < 4; ++q) {
            const int r = w * 32 + q * 8;
            gload16(p.Wt + (size_t)(r + srow) * H_ + kk + scol, Bs + r * 64);
        }
        __syncthreads();
#pragma unroll
        for (int ks = 0; ks < 2; ++ks) {
            short8 af[2], bfr[4];
#pragma unroll
            for (int i = 0; i < 2; ++i)
                af[i] = *(const short8*)(As + (wr * 32 + i * 16 + l15) * 64 + ks * 32 + 8 * lk);
#pragma unroll
            for (int j = 0; j < 4; ++j)
                bfr[j] = *(const short8*)(Bs + (wc * 64 + j * 16 + l15) * 64 + ks * 32 + 8 * lk);
#pragma unroll
            for (int i = 0; i < 2; ++i)
#pragma unroll
                for (int j = 0; j < 4; ++j)
                    acc[i][j] = __builtin_amdgcn_mfma_f32_16x16x32_bf16(af[i], bfr[j], acc[i][j], 0, 0, 0);
        }
        __syncthreads();
    }

#pragma unroll
    for (int i = 0; i < 2; ++i)
#pragma unroll
        for (int jj = 0; jj < 4; ++jj) {
            float s = acc[i][0][jj] * acc[i][0][jj] + acc[i][1][jj] * acc[i][1][jj]
                    + acc[i][2][jj] * acc[i][2][jj] + acc[i][3][jj] * acc[i][3][jj];
#pragma unroll
            for (int off = 1; off < 16; off <<= 1) s += __shfl_xor(s, off);
            if (l15 == 0) rowss[wr * 32 + i * 16 + 4 * lk + jj][wc] = s;
        }
    __syncthreads();

    const int bb4 = ((m_base >> 11) << 2) + 2;
#pragma unroll
    for (int i = 0; i < 2; ++i)
#pragma unroll
        for (int j = 0; j < 4; ++j)
#pragma unroll
            for (int jj = 0; jj < 4; ++jj) {
                const int lr = wr * 32 + i * 16 + 4 * lk + jj;
                const int r  = m_base + lr;
                const int n  = wc * 64 + j * 16 + l15;
                const float v = acc[i][j][jj];
                const float ss = rowss[lr][0] + rowss[lr][1];
                const float sc = 1.f / fmaxf(sqrtf(ss), 1e-8f);
                p.outF[(size_t)r * K_ + n] = v;
                p.outH[(size_t)(r + bb4) * K_ + n] = f2b(v);
                p.outN[(size_t)r * K_ + n] = f2b(v * sc);
            }
}

// ---------------- LayerNorm(conv_out + residual) -> bf16 ----------------

__global__ __launch_bounds__(192) void k_ln(const ushort* __restrict__ conv,
                                            const float* __restrict__ rep,
                                            const float* __restrict__ gw,
                                            const float* __restrict__ bw,
                                            ushort* __restrict__ out) {
    const int row = blockIdx.x;
    const int tid = threadIdx.x;
    const int h = tid * 4;
    const ushort4 cv = *(const ushort4*)(conv + (size_t)row * H_ + h);
    const float4  rv = *(const float4*)(rep + (size_t)row * H_ + h);
    float v[4] = { b2f(cv.x) + rv.x, b2f(cv.y) + rv.y, b2f(cv.z) + rv.z, b2f(cv.w) + rv.w };
    float s1 = v[0] + v[1] + v[2] + v[3];
    float s2 = v[0]*v[0] + v[1]*v[1] + v[2]*v[2] + v[3]*v[3];
#pragma unroll
    for (int off = 32; off; off >>= 1) { s1 += __shfl_xor(s1, off); s2 += __shfl_xor(s2, off); }
    __shared__ float sh[6];
    const int wid = tid >> 6, lane = tid & 63;
    if (lane == 0) { sh[wid] = s1; sh[3 + wid] = s2; }
    __syncthreads();
    s1 = sh[0] + sh[1] + sh[2];
    s2 = sh[3] + sh[4] + sh[5];
    const float mu  = s1 * (1.f / H_);
    const float var = s2 * (1.f / H_) - mu * mu;
    const float rs  = rsqrtf(var + 1e-5f);
    const float4 gv = *(const float4*)(gw + h);
    const float4 bv = *(const float4*)(bw + h);
    ushort4 o;
    o.x = f2b((v[0] - mu) * rs * gv.x + bv.x);
    o.y = f2b((v[1] - mu) * rs * gv.y + bv.y);
    o.z = f2b((v[2] - mu) * rs * gv.z + bv.z);
    o.w = f2b((v[3] - mu) * rs * gv.w + bv.w);
    *(ushort4*)(out + (size_t)row * H_ + h) = o;
}

// ---------------- banded cosine-sim + tags (fused; band-skip for compute) --------------

__global__ __launch_bounds__(256) void k_simtags(const ushort* __restrict__ normed,
                                                 const float* __restrict__ mask,
                                                 const int* __restrict__ Lp,
                                                 float* __restrict__ dis,
                                                 float* __restrict__ tags) {
    const int wid = threadIdx.x >> 6, lane = threadIdx.x & 63;
    const int l15 = lane & 15, lk = lane >> 4;
    const int b   = blockIdx.z;
    const int i0b = blockIdx.x * 64;
    const int i0  = i0b + wid * 16;
    const int j0  = blockIdx.y * 64;
    const int L   = *Lp;
    f32x4 acc[4] = {};
    if ((j0 + 63 >= i0b + 1) && (j0 <= i0b + 63 + L)) {
        const ushort* nb = normed + (size_t)b * S_ * K_;
#pragma unroll
        for (int kt = 0; kt < 4; ++kt) {
            const int kk = kt * 32;
            const short8 a = *(const short8*)(nb + (size_t)(i0 + l15) * K_ + kk + 8 * lk);
#pragma unroll
            for (int j = 0; j < 4; ++j) {
                const short8 bfr = *(const short8*)(nb + (size_t)(j0 + j * 16 + l15) * K_ + kk + 8 * lk);
                acc[j] = __builtin_amdgcn_mfma_f32_16x16x32_bf16(a, bfr, acc[j], 0, 0, 0);
            }
        }
    }
    const float* mb = mask + b * S_;
    float* dp = dis  + (size_t)b * S_ * S_;
    float* tp = tags + (size_t)b * S_ * S_;
#pragma unroll
    for (int j = 0; j < 4; ++j) {
#pragma unroll
        for (int jj = 0; jj < 4; ++jj) {
            const int i  = i0 + 4 * lk + jj;
            const int jc = j0 + j * 16 + l15;
            const int d  = jc - i;
            const bool band = (d >= 1 && d <= L);
            dp[(size_t)i * S_ + jc] = band ? acc[j][jj] : 0.f;
            tp[(size_t)i * S_ + jc] = band ? mb[i] * mb[jc] : 0.f;
        }
    }
}

// ---------------- host launch ----------------

extern "C" void kernel_launch(void* const* d_in, const int* in_sizes, int n_in,
                              void* d_out, int out_size, void* d_ws, size_t ws_size,
                              hipStream_t stream) {
    const float* rep  = (const float*)d_in[0];
    const float* mask = (const float*)d_in[1];
    const float* ew1  = (const float*)d_in[2];
    const float* ew3  = (const float*)d_in[3];
    const float* ew5  = (const float*)d_in[4];
    const float* lng  = (const float*)d_in[5];
    const float* lnb  = (const float*)d_in[6];
    const float* elin = (const float*)d_in[7];
    const float* etr  = (const float*)d_in[8];
    const float* dtr  = (const float*)d_in[9];
    const float* dw1  = (const float*)d_in[10];
    const float* dw3  = (const float*)d_in[11];
    const float* dw5  = (const float*)d_in[12];
    const float* dlin = (const float*)d_in[13];
    const float* olin = (const float*)d_in[14];

    float* out_loc = (float*)d_out;
    float* out_dis = out_loc + (size_t)B_ * S_ * K_;
    float* out_tag = out_dis + (size_t)B_ * S_ * S_;
    float* out_dec = out_tag + (size_t)B_ * S_ * S_;

    char* ws = (char*)d_ws;
    size_t off = 0;
    auto alloc = [&](size_t bytes) -> char* {
        char* p = ws + off;
        off += (bytes + 255) & ~(size_t)255;
        return p;
    };
    int*    Lp    = (int*)alloc(256);
    ushort* Xh    = (ushort*)alloc((size_t)B_ * SH_ * H_ * 2);   // halo'd rep
    ushort* bufLh = (ushort*)alloc((size_t)B_ * SH_ * K_ * 2);   // halo'd location
    ushort* wte1  = (ushort*)alloc((size_t)C_ * 768 * 2);
    ushort* wte3  = (ushort*)alloc((size_t)C_ * 2304 * 2);
    ushort* wte5  = (ushort*)alloc((size_t)C_ * 3840 * 2);
    ushort* wtd1  = (ushort*)alloc((size_t)C_ * 768 * 2);
    ushort* wtd3  = (ushort*)alloc((size_t)C_ * 2304 * 2);
    ushort* wtd5  = (ushort*)alloc((size_t)C_ * 3840 * 2);
    ushort* welin = (ushort*)alloc((size_t)H_ * H_ * 2);
    ushort* wetr  = (ushort*)alloc((size_t)K_ * H_ * 2);
    ushort* dtrT  = (ushort*)alloc((size_t)K_ * H_ * 2);         // dec_tr^T [128][768]
    ushort* wdlin = (ushort*)alloc((size_t)H_ * H_ * 2);
    ushort* wolin = (ushort*)alloc((size_t)H_ * H_ * 2);
    ushort* Wc    = (ushort*)alloc((size_t)H_ * 640 * 2);        // combined dec conv [768][640]
    ushort* bufB  = (ushort*)alloc((size_t)MTOK * H_ * 2);
    ushort* bufC  = (ushort*)alloc((size_t)MTOK * H_ * 2);
    ushort* bufD  = (ushort*)alloc((size_t)MTOK * H_ * 2);
    ushort* bufN  = (ushort*)alloc((size_t)MTOK * K_ * 2);
    if (ws_size < off) return;

    // 1. fused prep: maxlen + halo zero + halo'd rep + weight cvts + Wc zero-fill
    PrepP pp;
    pp.mask = mask; pp.Lp = Lp; pp.lh = bufLh;
    pp.rep = rep; pp.xh = Xh;
    pp.e[0]  = { ew1,  wte1, 768 * C_,  768,  C_ };
    pp.e[1]  = { ew3,  wte3, 2304 * C_, 2304, C_ };
    pp.e[2]  = { ew5,  wte5, 3840 * C_, 3840, C_ };
    pp.e[3]  = { dw1,  wtd1, 768 * C_,  768,  C_ };
    pp.e[4]  = { dw3,  wtd3, 2304 * C_, 2304, C_ };
    pp.e[5]  = { dw5,  wtd5, 3840 * C_, 3840, C_ };
    pp.e[6]  = { elin, welin, H_ * H_, 0, 0 };
    pp.e[7]  = { etr,  wetr,  K_ * H_, 0, 0 };
    pp.e[8]  = { dlin, wdlin, H_ * H_, 0, 0 };
    pp.e[9]  = { olin, wolin, H_ * H_, 0, 0 };
    pp.e[10] = { dtr,  dtrT,  K_ * H_, 768, K_ };
    pp.e[11] = { nullptr, Wc, H_ * 640, -1, 0 };
    k_prep<<<dim3(2048, 13), 256, 0, stream>>>(pp);

    // 2. composite decoder conv weights -> Wc[768][640]
    {
        CompP cp; cp.dtrT = dtrT;
        cp.e[0] = { wtd1, 768,  0, Wc + (size_t)0 * 640,   640, 2 * 128 };
        for (int t = 0; t < 3; ++t)
            cp.e[1 + t] = { wtd3, 2304, t * 768, Wc + (size_t)256 * 640, 640, (1 + t) * 128 };
        for (int t = 0; t < 5; ++t)
            cp.e[4 + t] = { wtd5, 3840, t * 768, Wc + (size_t)512 * 640, 640, t * 128 };
        k_compw<<<dim3(2, 9), 256, 0, stream>>>(cp);
    }

    // 3. encoder convs -> bufB  (g3b: 2 blocks/CU, BN=256 preserved)
    {
        G3P p{}; p.A = Xh; p.W0 = wte1; p.W1 = wte3; p.W2 = wte5;
        p.lda = H_; p.outB = bufB; p.ldoB = H_;
        g3b<<<768, 256, 0, stream>>>(p);
    }
    // 4. LN(conv + rep) -> bufC
    k_ln<<<MTOK, 192, 0, stream>>>(bufB, rep, lng, lnb, bufC);
    // 5. h2 = tanh(h_ln @ enc_lin^T) -> bufD
    {
        G4P p{}; p.A = bufC; p.W = welin; p.Ktot = H_; p.lda = H_;
        p.outB = bufD; p.ldoB = H_; p.act = 1;
        g4<<<dim3(MTOK / 128, H_ / 192), 256, 0, stream>>>(p);
    }
    // 6. location -> out_loc + bufLh + bufN (fused normalize)
    {
        GLP p{ bufD, wetr, out_loc, bufLh, bufN };
        gemm_loc<<<MTOK / 64, 256, 0, stream>>>(p);
    }
    // 7. decoder convs as ONE uniform GEMM: d1 = window(bufLh) @ Wc^T -> bufB
    {
        G4P p{}; p.A = bufLh; p.W = Wc; p.Ktot = 640; p.lda = K_;
        p.outB = bufB; p.ldoB = H_; p.haloA = 1;
        g4<<<dim3(MTOK / 128, H_ / 192), 256, 0, stream>>>(p);
    }
    // 8. d2 = tanh(d1 @ dec_lin^T) -> bufC
    {
        G4P p{}; p.A = bufB; p.W = wdlin; p.Ktot = H_; p.lda = H_;
        p.outB = bufC; p.ldoB = H_; p.act = 1;
        g4<<<dim3(MTOK / 128, H_ / 192), 256, 0, stream>>>(p);
    }
    // 9. decode_out = d2 @ out_lin^T -> out_dec
    {
        G4P p{}; p.A = bufC; p.W = wolin; p.Ktot = H_; p.lda = H_;
        p.outF = out_dec; p.ldoF = H_;
        g4<<<dim3(MTOK / 128, H_ / 192), 256, 0, stream>>>(p);
    }
    // 10. banded cosine sim + tags
    k_simtags<<<dim3(S_ / 64, S_ / 64, B_), 256, 0, stream>>>(bufN, mask, Lp, out_dis, out_tag);
}

// Round 13
// 371.120 us; speedup vs baseline: 1.0337x; 1.0337x over previous
//
#include <hip/hip_runtime.h>

#define B_   8
#define S_   2048
#define H_   768
#define K_   128
#define C_   256
#define SH_  2052              // S + 4 halo rows (2 each side)
#define MTOK (B_*S_)           // 16384 tokens

typedef __attribute__((ext_vector_type(8))) short short8;
typedef __attribute__((ext_vector_type(4))) float f32x4;

typedef __attribute__((address_space(1))) const void gvoid;
typedef __attribute__((address_space(3))) void lvoid;

__device__ __forceinline__ void gload16(const void* g, void* l) {
    __builtin_amdgcn_global_load_lds((gvoid*)g, (lvoid*)l, 16, 0, 0);
}

__device__ __forceinline__ ushort f2b(float f) {
    union { float f; unsigned u; } v; v.f = f;
    unsigned r = v.u + 0x7fffu + ((v.u >> 16) & 1u);   // RNE
    return (ushort)(r >> 16);
}
__device__ __forceinline__ float b2f(ushort u) {
    union { unsigned u; float f; } v; v.u = ((unsigned)u) << 16;
    return v.f;
}
__device__ __forceinline__ float fast_tanh(float x) {
    float e = __expf(2.f * x);
    return 1.f - 2.f / (e + 1.f);
}

// ---------------- k_prep: maxlen + halo-zero + build_xh + all weight cvts, one launch --

struct CvtE { const float* src; ushort* dst; int n; int kh; int sld; };

struct PrepP {
    const float* mask; int* Lp; ushort* lh;     // y=0, bx=0
    const float* rep;  ushort* xh;              // y=0, bx>0
    CvtE e[11];                                 // y=1..11
};

__global__ __launch_bounds__(256) void k_prep(PrepP p) {
    const int tid = threadIdx.x;
    const int y = blockIdx.y;
    if (y == 0) {
        if (blockIdx.x == 0) {
            __shared__ float sh[4];
            float mx = 0.f;
            for (int b = 0; b < B_; ++b) {
                float s = 0.f;
                for (int q = tid; q < 512; q += 256) {
                    const float4 v = ((const float4*)(p.mask + b * S_))[q];
                    s += v.x + v.y + v.z + v.w;
                }
#pragma unroll
                for (int off = 32; off; off >>= 1) s += __shfl_xor(s, off);
                if ((tid & 63) == 0) sh[tid >> 6] = s;
                __syncthreads();
                if (tid == 0) mx = fmaxf(mx, sh[0] + sh[1] + sh[2] + sh[3]);
                __syncthreads();
            }
            if (tid == 0) *p.Lp = (int)mx;
            for (int i = tid; i < B_ * 4 * K_; i += 256) {
                const int b = i >> 9;
                const int rc = i & 511;
                const int rr = rc >> 7;
                const int cc = rc & 127;
                const int row = (rr < 2) ? rr : (2048 + rr);
                p.lh[((size_t)b * SH_ + row) * K_ + cc] = 0;
            }
        } else {
            int i = (blockIdx.x - 1) * 256 + tid;
            const int stride = (gridDim.x - 1) * 256;
            const int n4 = B_ * SH_ * H_ / 4;
            for (; i < n4; i += stride) {
                const int idx = i * 4;
                const int h = idx % H_;
                const int rs = idx / H_;
                const int s = rs % SH_;
                const int b = rs / SH_;
                ushort4 o; o.x = 0; o.y = 0; o.z = 0; o.w = 0;
                if (s >= 2 && s < S_ + 2) {
                    const float4 v = *(const float4*)(p.rep + ((size_t)b * S_ + (s - 2)) * H_ + h);
                    o.x = f2b(v.x); o.y = f2b(v.y); o.z = f2b(v.z); o.w = f2b(v.w);
                }
                *(ushort4*)(p.xh + idx) = o;
            }
        }
    } else {
        const CvtE e = p.e[y - 1];
        int i = blockIdx.x * 256 + tid;
        const int stride = gridDim.x * 256;
        for (; i < e.n; i += stride) {
            if (e.kh) {
                const int c = i / e.kh;
                const int r = i - c * e.kh;
                e.dst[i] = f2b(e.src[r * e.sld + c]);
            } else {
                e.dst[i] = f2b(e.src[i]);
            }
        }
    }
}

// ---------------- k_compw: composite decoder weights w'[t] = dec_tr^T @ w[t] ----------

struct CompE { const ushort* w; int wld; int woff; ushort* o; int old_; int koff; };
struct CompP { const ushort* dtrT; CompE e[9]; };

__global__ __launch_bounds__(256) void k_compw(CompP p) {
    __shared__ __align__(16) ushort As[128 * 64];
    __shared__ __align__(16) ushort Bs[128 * 64];
    const CompE e = p.e[blockIdx.y];
    const int tid = threadIdx.x;
    const int w = tid >> 6, lane = tid & 63;
    const int l15 = lane & 15, lk = lane >> 4;
    const int wr = w >> 1, wc = w & 1;
    const int n_base = blockIdx.x * 128;
    f32x4 acc[4][4] = {};
    const int srow = lane >> 3;
    const int scol = (lane & 7) * 8;

    for (int kt = 0; kt < 12; ++kt) {
        const int kk = kt << 6;
#pragma unroll
        for (int q = 0; q < 4; ++q) {
            const int r = w * 32 + q * 8;
            gload16(p.dtrT + (size_t)(r + srow) * 768 + kk + scol, As + r * 64);
            gload16(e.w + (size_t)(n_base + r + srow) * e.wld + e.woff + kk + scol, Bs + r * 64);
        }
        __syncthreads();
#pragma unroll
        for (int ks = 0; ks < 2; ++ks) {
            short8 af[4], bfr[4];
#pragma unroll
            for (int i = 0; i < 4; ++i)
                af[i] = *(const short8*)(As + (wr * 64 + i * 16 + l15) * 64 + ks * 32 + 8 * lk);
#pragma unroll
            for (int j = 0; j < 4; ++j)
                bfr[j] = *(const short8*)(Bs + (wc * 64 + j * 16 + l15) * 64 + ks * 32 + 8 * lk);
#pragma unroll
            for (int i = 0; i < 4; ++i)
#pragma unroll
                for (int j = 0; j < 4; ++j)
                    acc[i][j] = __builtin_amdgcn_mfma_f32_16x16x32_bf16(af[i], bfr[j], acc[i][j], 0, 0, 0);
        }
        __syncthreads();
    }
#pragma unroll
    for (int i = 0; i < 4; ++i)
#pragma unroll
        for (int j = 0; j < 4; ++j)
#pragma unroll
            for (int jj = 0; jj < 4; ++jj) {
                const int jr = wr * 64 + i * 16 + 4 * lk + jj;
                const int c  = n_base + wc * 64 + j * 16 + l15;
                e.o[(size_t)c * e.old_ + e.koff + jr] = f2b(acc[i][j][jj]);
            }
}

// ---------------- g3: 8-wave, 3-deep-ring, counted-vmcnt conv GEMM --------------------
// BM=128, BN=256, BK=64, 512 threads (2x4 waves, wave 64x64).

struct G3P {
    const ushort* A;
    const ushort* W0;   // k=1 weights [256][1*KD]
    const ushort* W1;   // k=3 [256][3*KD]
    const ushort* W2;   // k=5 [256][5*KD]
    int lda;
    ushort* outB; int ldoB;
    int nMtiles;        // MTOK/128
};

template<bool DEC>
__global__ __launch_bounds__(512, 2) void g3(G3P p) {
    constexpr int TPT = DEC ? 2 : 12;        // K-tiles per tap
    constexpr int LDA = DEC ? 128 : 768;
    constexpr int ASEG = 1024;               // 128 rows x 8 (16B segs)
    constexpr int BSEG = 2048;               // 256 rows x 8
    constexpr int BUFE = (ASEG + BSEG) * 8;
    __shared__ __align__(16) ushort lds[3][BUFE];

    const int tid = threadIdx.x;
    const int w = tid >> 6, lane = tid & 63;
    const int l15 = lane & 15, lk = lane >> 4;
    const int wr = w >> 2, wc = w & 3;
    const int axor = l15 & 7;

    const int nM = p.nMtiles;
    int idx = blockIdx.x;
    int br;
    if (idx < nM) br = 2;                          // k=5 first (long pole)
    else if (idx < 2 * nM) { br = 1; idx -= nM; }
    else { br = 0; idx -= 2 * nM; }
    const int m_base = idx * 128;
    const int n_base = br * 256;
    const int nt = TPT * (2 * br + 1);
    const int Ktot = LDA * (2 * br + 1);
    const ushort* Wt = (br == 0) ? p.W0 : (br == 1) ? p.W1 : p.W2;
    const int arow0 = m_base + ((m_base >> 11) << 2) + (2 - br);

    auto stage1 = [&](int kt, int bufi, int q) {
        const int tap = kt / TPT;
        const int h0 = (kt - tap * TPT) << 6;
        if (q < 2) {
            const int seg = q * 512 + tid;
            const int row = seg >> 3;
            const int slot = (seg & 7) ^ (row & 7);
            gload16(p.A + (size_t)(arow0 + tap + row) * LDA + h0 + slot * 8,
                    &lds[bufi][seg * 8]);
        } else {
            const int seg = (q - 2) * 512 + tid;
            const int row = seg >> 3;
            const int slot = (seg & 7) ^ (row & 7);
            gload16(Wt + (size_t)row * Ktot + (kt << 6) + slot * 8,
                    &lds[bufi][ASEG * 8 + seg * 8]);
        }
    };
    auto stage = [&](int kt, int bufi) {
#pragma unroll
        for (int q = 0; q < 6; ++q) stage1(kt, bufi, q);
    };

    f32x4 acc[4][4] = {};

    stage(0, 0);
    stage(1, 1);

    int buf = 0;
    for (int t = 0; t < nt; ++t) {
        const ushort* Ab = &lds[buf][0];
        const ushort* Bb = &lds[buf][ASEG * 8];
        if (t + 1 < nt) asm volatile("s_waitcnt vmcnt(6)" ::: "memory");
        else            asm volatile("s_waitcnt vmcnt(0)" ::: "memory");
        __builtin_amdgcn_sched_barrier(0);
        asm volatile("s_barrier" ::: "memory");
        __builtin_amdgcn_sched_barrier(0);

        int nbuf = buf + 2; if (nbuf >= 3) nbuf -= 3;
        const bool sb = (t + 2 < nt);

#pragma unroll
        for (int ks = 0; ks < 2; ++ks) {
            short8 bq[4], aq[4];
#pragma unroll
            for (int ni = 0; ni < 4; ++ni)
                bq[ni] = *(const short8*)(Bb + (wc * 64 + ni * 16 + l15) * 64 + ((((ks << 2) | lk) ^ axor) << 3));
#pragma unroll
            for (int mi = 0; mi < 4; ++mi)
                aq[mi] = *(const short8*)(Ab + (wr * 64 + mi * 16 + l15) * 64 + ((((ks << 2) | lk) ^ axor) << 3));
            if (sb) { stage1(t + 2, nbuf, 3 * ks); stage1(t + 2, nbuf, 3 * ks + 1); stage1(t + 2, nbuf, 3 * ks + 2); }
            asm volatile("s_waitcnt lgkmcnt(0)" ::: "memory");
            __builtin_amdgcn_sched_barrier(0);
            __builtin_amdgcn_s_setprio(1);
#pragma unroll
            for (int mi = 0; mi < 4; ++mi)
#pragma unroll
                for (int ni = 0; ni < 4; ++ni)
                    acc[mi][ni] = __builtin_amdgcn_mfma_f32_16x16x32_bf16(aq[mi], bq[ni], acc[mi][ni], 0, 0, 0);
            __builtin_amdgcn_s_setprio(0);
            __builtin_amdgcn_sched_barrier(0);
        }
        ++buf; if (buf == 3) buf = 0;
    }

#pragma unroll
    for (int mi = 0; mi < 4; ++mi)
#pragma unroll
        for (int ni = 0; ni < 4; ++ni)
#pragma unroll
            for (int jj = 0; jj < 4; ++jj) {
                const int r = m_base + wr * 64 + mi * 16 + 4 * lk + jj;
                const int n = n_base + wc * 64 + ni * 16 + l15;
                p.outB[(size_t)r * p.ldoB + n] = f2b(acc[mi][ni][jj]);
            }
}

// ---------------- g4: 4-wave, BM=128 BN=192, 2-deep ring, 2 blocks/CU (linears) --------

struct G4P {
    const ushort* A;
    const ushort* W;
    int Ktot;
    int lda;
    ushort* outB; int ldoB;
    float*  outF; int ldoF;
    int act;
};

__global__ __launch_bounds__(256, 2) void g4(G4P p) {
    constexpr int ASEG = 1024;   // 128 rows x 8
    constexpr int BSEG = 1536;   // 192 rows x 8
    __shared__ __align__(16) ushort lds[2][(ASEG + BSEG) * 8];   // 80 KB total

    const int tid = threadIdx.x;
    const int w = tid >> 6, lane = tid & 63;
    const int l15 = lane & 15, lk = lane >> 4;
    const int wr = w >> 1, wc = w & 1;
    const int axor = l15 & 7;
    const int m_base = blockIdx.x * 128;
    const int n_base = blockIdx.y * 192;
    const int nt = p.Ktot >> 6;

    auto stage = [&](int kt, int bufi) {
        const int kk = kt << 6;
        ushort* Ab = &lds[bufi][0];
        ushort* Bb = &lds[bufi][ASEG * 8];
#pragma unroll
        for (int q = 0; q < 4; ++q) {
            const int seg = q * 256 + tid;
            const int row = seg >> 3;
            const int s = (seg & 7) ^ (row & 7);
            gload16(p.A + (size_t)(m_base + row) * p.lda + kk + s * 8, Ab + seg * 8);
        }
#pragma unroll
        for (int q = 0; q < 6; ++q) {
            const int seg = q * 256 + tid;
            const int row = seg >> 3;
            const int s = (seg & 7) ^ (row & 7);
            gload16(p.W + (size_t)(n_base + row) * p.Ktot + kk + s * 8, Bb + seg * 8);
        }
    };

    f32x4 acc[4][6] = {};

    stage(0, 0);
    stage(1, 1);

    for (int t = 0; t < nt; ++t) {
        const int cur = t & 1;
        const ushort* Ab = &lds[cur][0];
        const ushort* Bb = &lds[cur][ASEG * 8];
        if (t + 1 < nt) asm volatile("s_waitcnt vmcnt(10)" ::: "memory");
        else            asm volatile("s_waitcnt vmcnt(0)" ::: "memory");
        __builtin_amdgcn_sched_barrier(0);
        asm volatile("s_barrier" ::: "memory");
        __builtin_amdgcn_sched_barrier(0);

        short8 af[4][2], bf[6][2];
#pragma unroll
        for (int mi = 0; mi < 4; ++mi)
#pragma unroll
            for (int ks = 0; ks < 2; ++ks)
                af[mi][ks] = *(const short8*)(Ab + (wr * 64 + mi * 16 + l15) * 64 + ((((ks << 2) | lk) ^ axor) << 3));
#pragma unroll
        for (int ni = 0; ni < 6; ++ni)
#pragma unroll
            for (int ks = 0; ks < 2; ++ks)
                bf[ni][ks] = *(const short8*)(Bb + (wc * 96 + ni * 16 + l15) * 64 + ((((ks << 2) | lk) ^ axor) << 3));
        asm volatile("s_waitcnt lgkmcnt(0)" ::: "memory");
        __builtin_amdgcn_sched_barrier(0);
        asm volatile("s_barrier" ::: "memory");
        __builtin_amdgcn_sched_barrier(0);
        if (t + 2 < nt) stage(t + 2, cur);
        __builtin_amdgcn_sched_barrier(0);
        __builtin_amdgcn_s_setprio(1);
#pragma unroll
        for (int mi = 0; mi < 4; ++mi)
#pragma unroll
            for (int ni = 0; ni < 6; ++ni) {
                acc[mi][ni] = __builtin_amdgcn_mfma_f32_16x16x32_bf16(af[mi][0], bf[ni][0], acc[mi][ni], 0, 0, 0);
                acc[mi][ni] = __builtin_amdgcn_mfma_f32_16x16x32_bf16(af[mi][1], bf[ni][1], acc[mi][ni], 0, 0, 0);
            }
        __builtin_amdgcn_s_setprio(0);
        __builtin_amdgcn_sched_barrier(0);
    }

#pragma unroll
    for (int mi = 0; mi < 4; ++mi)
#pragma unroll
        for (int ni = 0; ni < 6; ++ni)
#pragma unroll
            for (int jj = 0; jj < 4; ++jj) {
                const int r = m_base + wr * 64 + mi * 16 + 4 * lk + jj;
                const int n = n_base + wc * 96 + ni * 16 + l15;
                float v = acc[mi][ni][jj];
                if (p.act) v = fast_tanh(v);
                if (p.outF) p.outF[(size_t)r * p.ldoF + n] = v;
                if (p.outB) p.outB[(size_t)r * p.ldoB + n] = f2b(v);
            }
}

// ------- gemm_loc: location GEMM (BM=64, BN=128, 2-phase) + fused row-normalize --------

struct GLP {
    const ushort* A;      // h2 [MTOK][768]
    const ushort* Wt;     // enc_tr [128][768]
    float* outF;          // location f32 [MTOK][128]
    ushort* outH;         // halo'd location bf16 [B][SH][128]
    ushort* outN;         // normed bf16 [MTOK][128]
};

__global__ __launch_bounds__(256) void gemm_loc(GLP p) {
    __shared__ __align__(16) ushort As[64 * 64];
    __shared__ __align__(16) ushort Bs[128 * 64];
    __shared__ float rowss[64][2];
    const int tid = threadIdx.x;
    const int w = tid >> 6, lane = tid & 63;
    const int l15 = lane & 15, lk = lane >> 4;
    const int m_base = blockIdx.x * 64;
    const int wr = w >> 1, wc = w & 1;
    f32x4 acc[2][4] = {};
    const int srow = lane >> 3;
    const int scol = (lane & 7) * 8;

    for (int kt = 0; kt < 12; ++kt) {
        const int kk = kt << 6;
#pragma unroll
        for (int q = 0; q < 2; ++q) {
            const int r = w * 16 + q * 8;
            gload16(p.A + (size_t)(m_base + r + srow) * H_ + kk + scol, As + r * 64);
        }
#pragma unroll
        for (int q = 0; q < 4; ++q) {
            const int r = w * 32 + q * 8;
            gload16(p.Wt + (size_t)(r + srow) * H_ + kk + scol, Bs + r * 64);
        }
        __syncthreads();
#pragma unroll
        for (int ks = 0; ks < 2; ++ks) {
            short8 af[2], bfr[4];
#pragma unroll
            for (int i = 0; i < 2; ++i)
                af[i] = *(const short8*)(As + (wr * 32 + i * 16 + l15) * 64 + ks * 32 + 8 * lk);
#pragma unroll
            for (int j = 0; j < 4; ++j)
                bfr[j] = *(const short8*)(Bs + (wc * 64 + j * 16 + l15) * 64 + ks * 32 + 8 * lk);
#pragma unroll
            for (int i = 0; i < 2; ++i)
#pragma unroll
                for (int j = 0; j < 4; ++j)
                    acc[i][j] = __builtin_amdgcn_mfma_f32_16x16x32_bf16(af[i], bfr[j], acc[i][j], 0, 0, 0);
        }
        __syncthreads();
    }

#pragma unroll
    for (int i = 0; i < 2; ++i)
#pragma unroll
        for (int jj = 0; jj < 4; ++jj) {
            float s = acc[i][0][jj] * acc[i][0][jj] + acc[i][1][jj] * acc[i][1][jj]
                    + acc[i][2][jj] * acc[i][2][jj] + acc[i][3][jj] * acc[i][3][jj];
#pragma unroll
            for (int off = 1; off < 16; off <<= 1) s += __shfl_xor(s, off);
            if (l15 == 0) rowss[wr * 32 + i * 16 + 4 * lk + jj][wc] = s;
        }
    __syncthreads();

    const int bb4 = ((m_base >> 11) << 2) + 2;
#pragma unroll
    for (int i = 0; i < 2; ++i)
#pragma unroll
        for (int j = 0; j < 4; ++j)
#pragma unroll
            for (int jj = 0; jj < 4; ++jj) {
                const int lr = wr * 32 + i * 16 + 4 * lk + jj;
                const int r  = m_base + lr;
                const int n  = wc * 64 + j * 16 + l15;
                const float v = acc[i][j][jj];
                const float ss = rowss[lr][0] + rowss[lr][1];
                const float sc = 1.f / fmaxf(sqrtf(ss), 1e-8f);
                p.outF[(size_t)r * K_ + n] = v;
                p.outH[(size_t)(r + bb4) * K_ + n] = f2b(v);
                p.outN[(size_t)r * K_ + n] = f2b(v * sc);
            }
}

// ---------------- LayerNorm(conv_out + residual) -> bf16 ----------------

__global__ __launch_bounds__(192) void k_ln(const ushort* __restrict__ conv,
                                            const float* __restrict__ rep,
                                            const float* __restrict__ gw,
                                            const float* __restrict__ bw,
                                            ushort* __restrict__ out) {
    const int row = blockIdx.x;
    const int tid = threadIdx.x;
    const int h = tid * 4;
    const ushort4 cv = *(const ushort4*)(conv + (size_t)row * H_ + h);
    const float4  rv = *(const float4*)(rep + (size_t)row * H_ + h);
    float v[4] = { b2f(cv.x) + rv.x, b2f(cv.y) + rv.y, b2f(cv.z) + rv.z, b2f(cv.w) + rv.w };
    float s1 = v[0] + v[1] + v[2] + v[3];
    float s2 = v[0]*v[0] + v[1]*v[1] + v[2]*v[2] + v[3]*v[3];
#pragma unroll
    for (int off = 32; off; off >>= 1) { s1 += __shfl_xor(s1, off); s2 += __shfl_xor(s2, off); }
    __shared__ float sh[6];
    const int wid = tid >> 6, lane = tid & 63;
    if (lane == 0) { sh[wid] = s1; sh[3 + wid] = s2; }
    __syncthreads();
    s1 = sh[0] + sh[1] + sh[2];
    s2 = sh[3] + sh[4] + sh[5];
    const float mu  = s1 * (1.f / H_);
    const float var = s2 * (1.f / H_) - mu * mu;
    const float rs  = rsqrtf(var + 1e-5f);
    const float4 gv = *(const float4*)(gw + h);
    const float4 bv = *(const float4*)(bw + h);
    ushort4 o;
    o.x = f2b((v[0] - mu) * rs * gv.x + bv.x);
    o.y = f2b((v[1] - mu) * rs * gv.y + bv.y);
    o.z = f2b((v[2] - mu) * rs * gv.z + bv.z);
    o.w = f2b((v[3] - mu) * rs * gv.w + bv.w);
    *(ushort4*)(out + (size_t)row * H_ + h) = o;
}

// ---------------- banded cosine-sim + tags (fused; band-skip for compute) --------------

__global__ __launch_bounds__(256) void k_simtags(const ushort* __restrict__ normed,
                                                 const float* __restrict__ mask,
                                                 const int* __restrict__ Lp,
                                                 float* __restrict__ dis,
                                                 float* __restrict__ tags) {
    const int wid = threadIdx.x >> 6, lane = threadIdx.x & 63;
    const int l15 = lane & 15, lk = lane >> 4;
    const int b   = blockIdx.z;
    const int i0b = blockIdx.x * 64;
    const int i0  = i0b + wid * 16;
    const int j0  = blockIdx.y * 64;
    const int L   = *Lp;
    f32x4 acc[4] = {};
    if ((j0 + 63 >= i0b + 1) && (j0 <= i0b + 63 + L)) {
        const ushort* nb = normed + (size_t)b * S_ * K_;
#pragma unroll
        for (int kt = 0; kt < 4; ++kt) {
            const int kk = kt * 32;
            const short8 a = *(const short8*)(nb + (size_t)(i0 + l15) * K_ + kk + 8 * lk);
#pragma unroll
            for (int j = 0; j < 4; ++j) {
                const short8 bfr = *(const short8*)(nb + (size_t)(j0 + j * 16 + l15) * K_ + kk + 8 * lk);
                acc[j] = __builtin_amdgcn_mfma_f32_16x16x32_bf16(a, bfr, acc[j], 0, 0, 0);
            }
        }
    }
    const float* mb = mask + b * S_;
    float* dp = dis  + (size_t)b * S_ * S_;
    float* tp = tags + (size_t)b * S_ * S_;
#pragma unroll
    for (int j = 0; j < 4; ++j) {
#pragma unroll
        for (int jj = 0; jj < 4; ++jj) {
            const int i  = i0 + 4 * lk + jj;
            const int jc = j0 + j * 16 + l15;
            const int d  = jc - i;
            const bool band = (d >= 1 && d <= L);
            dp[(size_t)i * S_ + jc] = band ? acc[j][jj] : 0.f;
            tp[(size_t)i * S_ + jc] = band ? mb[i] * mb[jc] : 0.f;
        }
    }
}

// ---------------- host launch ----------------

extern "C" void kernel_launch(void* const* d_in, const int* in_sizes, int n_in,
                              void* d_out, int out_size, void* d_ws, size_t ws_size,
                              hipStream_t stream) {
    const float* rep  = (const float*)d_in[0];
    const float* mask = (const float*)d_in[1];
    const float* ew1  = (const float*)d_in[2];
    const float* ew3  = (const float*)d_in[3];
    const float* ew5  = (const float*)d_in[4];
    const float* lng  = (const float*)d_in[5];
    const float* lnb  = (const float*)d_in[6];
    const float* elin = (const float*)d_in[7];
    const float* etr  = (const float*)d_in[8];
    const float* dtr  = (const float*)d_in[9];
    const float* dw1  = (const float*)d_in[10];
    const float* dw3  = (const float*)d_in[11];
    const float* dw5  = (const float*)d_in[12];
    const float* dlin = (const float*)d_in[13];
    const float* olin = (const float*)d_in[14];

    float* out_loc = (float*)d_out;
    float* out_dis = out_loc + (size_t)B_ * S_ * K_;
    float* out_tag = out_dis + (size_t)B_ * S_ * S_;
    float* out_dec = out_tag + (size_t)B_ * S_ * S_;

    char* ws = (char*)d_ws;
    size_t off = 0;
    auto alloc = [&](size_t bytes) -> char* {
        char* p = ws + off;
        off += (bytes + 255) & ~(size_t)255;
        return p;
    };
    int*    Lp    = (int*)alloc(256);
    ushort* Xh    = (ushort*)alloc((size_t)B_ * SH_ * H_ * 2);   // halo'd rep
    ushort* bufLh = (ushort*)alloc((size_t)B_ * SH_ * K_ * 2);   // halo'd location
    ushort* wte1  = (ushort*)alloc((size_t)C_ * 768 * 2);
    ushort* wte3  = (ushort*)alloc((size_t)C_ * 2304 * 2);
    ushort* wte5  = (ushort*)alloc((size_t)C_ * 3840 * 2);
    ushort* wtd1  = (ushort*)alloc((size_t)C_ * 768 * 2);
    ushort* wtd3  = (ushort*)alloc((size_t)C_ * 2304 * 2);
    ushort* wtd5  = (ushort*)alloc((size_t)C_ * 3840 * 2);
    ushort* welin = (ushort*)alloc((size_t)H_ * H_ * 2);
    ushort* wetr  = (ushort*)alloc((size_t)K_ * H_ * 2);
    ushort* dtrT  = (ushort*)alloc((size_t)K_ * H_ * 2);         // dec_tr^T [128][768]
    ushort* wdlin = (ushort*)alloc((size_t)H_ * H_ * 2);
    ushort* wolin = (ushort*)alloc((size_t)H_ * H_ * 2);
    ushort* wc1   = (ushort*)alloc((size_t)C_ * 128 * 2);
    ushort* wc3   = (ushort*)alloc((size_t)C_ * 384 * 2);
    ushort* wc5   = (ushort*)alloc((size_t)C_ * 640 * 2);
    ushort* bufB  = (ushort*)alloc((size_t)MTOK * H_ * 2);
    ushort* bufC  = (ushort*)alloc((size_t)MTOK * H_ * 2);
    ushort* bufD  = (ushort*)alloc((size_t)MTOK * H_ * 2);
    ushort* bufN  = (ushort*)alloc((size_t)MTOK * K_ * 2);
    if (ws_size < off) return;

    // 1. fused prep: maxlen + bufLh halo zero + halo'd rep + all weight cvts
    PrepP pp;
    pp.mask = mask; pp.Lp = Lp; pp.lh = bufLh;
    pp.rep = rep; pp.xh = Xh;
    pp.e[0]  = { ew1,  wte1, 768 * C_,  768,  C_ };
    pp.e[1]  = { ew3,  wte3, 2304 * C_, 2304, C_ };
    pp.e[2]  = { ew5,  wte5, 3840 * C_, 3840, C_ };
    pp.e[3]  = { dw1,  wtd1, 768 * C_,  768,  C_ };
    pp.e[4]  = { dw3,  wtd3, 2304 * C_, 2304, C_ };
    pp.e[5]  = { dw5,  wtd5, 3840 * C_, 3840, C_ };
    pp.e[6]  = { elin, welin, H_ * H_, 0, 0 };
    pp.e[7]  = { etr,  wetr,  K_ * H_, 0, 0 };
    pp.e[8]  = { dlin, wdlin, H_ * H_, 0, 0 };
    pp.e[9]  = { olin, wolin, H_ * H_, 0, 0 };
    pp.e[10] = { dtr,  dtrT,  K_ * H_, 768, K_ };
    k_prep<<<dim3(2048, 12), 256, 0, stream>>>(pp);

    // 2. composite decoder conv weights
    {
        CompP cp; cp.dtrT = dtrT;
        cp.e[0] = { wtd1, 768,  0,        wc1, 128, 0 };
        for (int t = 0; t < 3; ++t) cp.e[1 + t] = { wtd3, 2304, t * 768, wc3, 384, t * 128 };
        for (int t = 0; t < 5; ++t) cp.e[4 + t] = { wtd5, 3840, t * 768, wc5, 640, t * 128 };
        k_compw<<<dim3(2, 9), 256, 0, stream>>>(cp);
    }

    // 3. encoder convs -> bufB
    {
        G3P p{}; p.A = Xh; p.W0 = wte1; p.W1 = wte3; p.W2 = wte5;
        p.lda = H_; p.outB = bufB; p.ldoB = H_; p.nMtiles = MTOK / 128;
        g3<false><<<3 * (MTOK / 128), 512, 0, stream>>>(p);
    }
    // 4. LN(conv + rep) -> bufC
    k_ln<<<MTOK, 192, 0, stream>>>(bufB, rep, lng, lnb, bufC);
    // 5. h2 = tanh(h_ln @ enc_lin^T) -> bufD
    {
        G4P p{}; p.A = bufC; p.W = welin; p.Ktot = H_; p.lda = H_;
        p.outB = bufD; p.ldoB = H_; p.act = 1;
        g4<<<dim3(MTOK / 128, H_ / 192), 256, 0, stream>>>(p);
    }
    // 6. location -> out_loc + bufLh + bufN (fused normalize)
    {
        GLP p{ bufD, wetr, out_loc, bufLh, bufN };
        gemm_loc<<<MTOK / 64, 256, 0, stream>>>(p);
    }
    // 7. decoder convs on location (composite weights) -> bufB
    {
        G3P p{}; p.A = bufLh; p.W0 = wc1; p.W1 = wc3; p.W2 = wc5;
        p.lda = K_; p.outB = bufB; p.ldoB = H_; p.nMtiles = MTOK / 128;
        g3<true><<<3 * (MTOK / 128), 512, 0, stream>>>(p);
    }
    // 8. d2 = tanh(d1 @ dec_lin^T) -> bufC
    {
        G4P p{}; p.A = bufB; p.W = wdlin; p.Ktot = H_; p.lda = H_;
        p.outB = bufC; p.ldoB = H_; p.act = 1;
        g4<<<dim3(MTOK / 128, H_ / 192), 256, 0, stream>>>(p);
    }
    // 9. decode_out = d2 @ out_lin^T -> out_dec
    {
        G4P p{}; p.A = bufC; p.W = wolin; p.Ktot = H_; p.lda = H_;
        p.outF = out_dec; p.ldoF = H_;
        g4<<<dim3(MTOK / 128, H_ / 192), 256, 0, stream>>>(p);
    }
    // 10. banded cosine sim + tags
    k_simtags<<<dim3(S_ / 64, S_ / 64, B_), 256, 0, stream>>>(bufN, mask, Lp, out_dis, out_tag);
}

// Round 14
// 369.311 us; speedup vs baseline: 1.0388x; 1.0049x over previous
//
#include <hip/hip_runtime.h>

#define B_   8
#define S_   2048
#define H_   768
#define K_   128
#define C_   256
#define SH_  2052              // S + 4 halo rows (2 each side)
#define MTOK (B_*S_)           // 16384 tokens

typedef __attribute__((ext_vector_type(8))) short short8;
typedef __attribute__((ext_vector_type(4))) float f32x4;

typedef __attribute__((address_space(1))) const void gvoid;
typedef __attribute__((address_space(3))) void lvoid;

__device__ __forceinline__ void gload16(const void* g, void* l) {
    __builtin_amdgcn_global_load_lds((gvoid*)g, (lvoid*)l, 16, 0, 0);
}

__device__ __forceinline__ ushort f2b(float f) {
    union { float f; unsigned u; } v; v.f = f;
    unsigned r = v.u + 0x7fffu + ((v.u >> 16) & 1u);   // RNE
    return (ushort)(r >> 16);
}
__device__ __forceinline__ float b2f(ushort u) {
    union { unsigned u; float f; } v; v.u = ((unsigned)u) << 16;
    return v.f;
}
__device__ __forceinline__ float fast_tanh(float x) {
    float e = __expf(2.f * x);
    return 1.f - 2.f / (e + 1.f);
}

// ---------------- k_prep: maxlen + halo-zero + build_xh + weight cvts + WcT zero -------

struct CvtE { const float* src; ushort* dst; int n; int kh; int sld; };  // kh<0: zero-fill

struct PrepP {
    const float* mask; int* Lp; ushort* lh;     // y=0, bx=0
    const float* rep;  ushort* xh;              // y=0, bx>0
    CvtE e[12];                                 // y=1..12
};

__global__ __launch_bounds__(256) void k_prep(PrepP p) {
    const int tid = threadIdx.x;
    const int y = blockIdx.y;
    if (y == 0) {
        if (blockIdx.x == 0) {
            __shared__ float sh[4];
            float mx = 0.f;
            for (int b = 0; b < B_; ++b) {
                float s = 0.f;
                for (int q = tid; q < 512; q += 256) {
                    const float4 v = ((const float4*)(p.mask + b * S_))[q];
                    s += v.x + v.y + v.z + v.w;
                }
#pragma unroll
                for (int off = 32; off; off >>= 1) s += __shfl_xor(s, off);
                if ((tid & 63) == 0) sh[tid >> 6] = s;
                __syncthreads();
                if (tid == 0) mx = fmaxf(mx, sh[0] + sh[1] + sh[2] + sh[3]);
                __syncthreads();
            }
            if (tid == 0) *p.Lp = (int)mx;
            for (int i = tid; i < B_ * 4 * K_; i += 256) {
                const int b = i >> 9;
                const int rc = i & 511;
                const int rr = rc >> 7;
                const int cc = rc & 127;
                const int row = (rr < 2) ? rr : (2048 + rr);
                p.lh[((size_t)b * SH_ + row) * K_ + cc] = 0;
            }
        } else {
            int i = (blockIdx.x - 1) * 256 + tid;
            const int stride = (gridDim.x - 1) * 256;
            const int n4 = B_ * SH_ * H_ / 4;
            for (; i < n4; i += stride) {
                const int idx = i * 4;
                const int h = idx % H_;
                const int rs = idx / H_;
                const int s = rs % SH_;
                const int b = rs / SH_;
                ushort4 o; o.x = 0; o.y = 0; o.z = 0; o.w = 0;
                if (s >= 2 && s < S_ + 2) {
                    const float4 v = *(const float4*)(p.rep + ((size_t)b * S_ + (s - 2)) * H_ + h);
                    o.x = f2b(v.x); o.y = f2b(v.y); o.z = f2b(v.z); o.w = f2b(v.w);
                }
                *(ushort4*)(p.xh + idx) = o;
            }
        }
    } else {
        const CvtE e = p.e[y - 1];
        int i = blockIdx.x * 256 + tid;
        const int stride = gridDim.x * 256;
        for (; i < e.n; i += stride) {
            if (e.kh < 0) {
                e.dst[i] = 0;
            } else if (e.kh) {
                const int c = i / e.kh;
                const int r = i - c * e.kh;
                e.dst[i] = f2b(e.src[r * e.sld + c]);
            } else {
                e.dst[i] = f2b(e.src[i]);
            }
        }
    }
}

// ---- k_compw: composite decoder weights into TRANSPOSED window form WcT[640][768] ----
// WcT[koff + j][chanoff + c] = sum_h dec_tr^T[j][h] * w_tap[c][h];  koff = window_pos*128.

struct CompE { const ushort* w; int wld; int woff; ushort* o; int old_; int koff; };
struct CompP { const ushort* dtrT; CompE e[9]; };

__global__ __launch_bounds__(256) void k_compw(CompP p) {
    __shared__ __align__(16) ushort As[128 * 64];
    __shared__ __align__(16) ushort Bs[128 * 64];
    const CompE e = p.e[blockIdx.y];
    const int tid = threadIdx.x;
    const int w = tid >> 6, lane = tid & 63;
    const int l15 = lane & 15, lk = lane >> 4;
    const int wr = w >> 1, wc = w & 1;
    const int n_base = blockIdx.x * 128;
    f32x4 acc[4][4] = {};
    const int srow = lane >> 3;
    const int scol = (lane & 7) * 8;

    for (int kt = 0; kt < 12; ++kt) {
        const int kk = kt << 6;
#pragma unroll
        for (int q = 0; q < 4; ++q) {
            const int r = w * 32 + q * 8;
            gload16(p.dtrT + (size_t)(r + srow) * 768 + kk + scol, As + r * 64);
            gload16(e.w + (size_t)(n_base + r + srow) * e.wld + e.woff + kk + scol, Bs + r * 64);
        }
        __syncthreads();
#pragma unroll
        for (int ks = 0; ks < 2; ++ks) {
            short8 af[4], bfr[4];
#pragma unroll
            for (int i = 0; i < 4; ++i)
                af[i] = *(const short8*)(As + (wr * 64 + i * 16 + l15) * 64 + ks * 32 + 8 * lk);
#pragma unroll
            for (int j = 0; j < 4; ++j)
                bfr[j] = *(const short8*)(Bs + (wc * 64 + j * 16 + l15) * 64 + ks * 32 + 8 * lk);
#pragma unroll
            for (int i = 0; i < 4; ++i)
#pragma unroll
                for (int j = 0; j < 4; ++j)
                    acc[i][j] = __builtin_amdgcn_mfma_f32_16x16x32_bf16(af[i], bfr[j], acc[i][j], 0, 0, 0);
        }
        __syncthreads();
    }
#pragma unroll
    for (int i = 0; i < 4; ++i)
#pragma unroll
        for (int j = 0; j < 4; ++j)
#pragma unroll
            for (int jj = 0; jj < 4; ++jj) {
                const int jr = wr * 64 + i * 16 + 4 * lk + jj;       // j index 0..127
                const int c  = n_base + wc * 64 + j * 16 + l15;      // channel 0..255 (in branch)
                e.o[(size_t)(e.koff + jr) * e.old_ + c] = f2b(acc[i][j][jj]);
            }
}

// ---- k_wz: Wz[o][k] = sum_c wdlin[o][c] * WcT[k][c]  (768 x 640, K=768) ----

__global__ __launch_bounds__(256) void k_wz(const ushort* __restrict__ wdlin,
                                            const ushort* __restrict__ WcT,
                                            ushort* __restrict__ Wz) {
    __shared__ __align__(16) ushort As[128 * 64];
    __shared__ __align__(16) ushort Bs[128 * 64];
    const int tid = threadIdx.x;
    const int w = tid >> 6, lane = tid & 63;
    const int l15 = lane & 15, lk = lane >> 4;
    const int wr = w >> 1, wc = w & 1;
    const int m_base = blockIdx.x * 128;       // o
    const int n_base = blockIdx.y * 128;       // k (window col)
    f32x4 acc[4][4] = {};
    const int srow = lane >> 3;
    const int scol = (lane & 7) * 8;

    for (int kt = 0; kt < 12; ++kt) {
        const int kk = kt << 6;
#pragma unroll
        for (int q = 0; q < 4; ++q) {
            const int r = w * 32 + q * 8;
            gload16(wdlin + (size_t)(m_base + r + srow) * 768 + kk + scol, As + r * 64);
            gload16(WcT + (size_t)(n_base + r + srow) * 768 + kk + scol, Bs + r * 64);
        }
        __syncthreads();
#pragma unroll
        for (int ks = 0; ks < 2; ++ks) {
            short8 af[4], bfr[4];
#pragma unroll
            for (int i = 0; i < 4; ++i)
                af[i] = *(const short8*)(As + (wr * 64 + i * 16 + l15) * 64 + ks * 32 + 8 * lk);
#pragma unroll
            for (int j = 0; j < 4; ++j)
                bfr[j] = *(const short8*)(Bs + (wc * 64 + j * 16 + l15) * 64 + ks * 32 + 8 * lk);
#pragma unroll
            for (int i = 0; i < 4; ++i)
#pragma unroll
                for (int j = 0; j < 4; ++j)
                    acc[i][j] = __builtin_amdgcn_mfma_f32_16x16x32_bf16(af[i], bfr[j], acc[i][j], 0, 0, 0);
        }
        __syncthreads();
    }
#pragma unroll
    for (int i = 0; i < 4; ++i)
#pragma unroll
        for (int j = 0; j < 4; ++j)
#pragma unroll
            for (int jj = 0; jj < 4; ++jj) {
                const int o = m_base + wr * 64 + i * 16 + 4 * lk + jj;
                const int k = n_base + wc * 64 + j * 16 + l15;
                Wz[(size_t)o * 640 + k] = f2b(acc[i][j][jj]);
            }
}

// ---------------- g3: 8-wave, 3-deep-ring, counted-vmcnt conv GEMM (encoder) ----------
// BM=128, BN=256, BK=64, 512 threads (2x4 waves, wave 64x64).

struct G3P {
    const ushort* A;
    const ushort* W0;   // k=1 weights [256][768]
    const ushort* W1;   // k=3 [256][2304]
    const ushort* W2;   // k=5 [256][3840]
    int lda;
    ushort* outB; int ldoB;
    int nMtiles;        // MTOK/128
};

__global__ __launch_bounds__(512, 2) void g3(G3P p) {
    constexpr int TPT = 12;
    constexpr int LDA = 768;
    constexpr int ASEG = 1024;               // 128 rows x 8 (16B segs)
    constexpr int BSEG = 2048;               // 256 rows x 8
    constexpr int BUFE = (ASEG + BSEG) * 8;
    __shared__ __align__(16) ushort lds[3][BUFE];

    const int tid = threadIdx.x;
    const int w = tid >> 6, lane = tid & 63;
    const int l15 = lane & 15, lk = lane >> 4;
    const int wr = w >> 2, wc = w & 3;
    const int axor = l15 & 7;

    const int nM = p.nMtiles;
    int idx = blockIdx.x;
    int br;
    if (idx < nM) br = 2;                          // k=5 first (long pole)
    else if (idx < 2 * nM) { br = 1; idx -= nM; }
    else { br = 0; idx -= 2 * nM; }
    const int m_base = idx * 128;
    const int n_base = br * 256;
    const int nt = TPT * (2 * br + 1);
    const int Ktot = LDA * (2 * br + 1);
    const ushort* Wt = (br == 0) ? p.W0 : (br == 1) ? p.W1 : p.W2;
    const int arow0 = m_base + ((m_base >> 11) << 2) + (2 - br);

    auto stage1 = [&](int kt, int bufi, int q) {
        const int tap = kt / TPT;
        const int h0 = (kt - tap * TPT) << 6;
        if (q < 2) {
            const int seg = q * 512 + tid;
            const int row = seg >> 3;
            const int slot = (seg & 7) ^ (row & 7);
            gload16(p.A + (size_t)(arow0 + tap + row) * LDA + h0 + slot * 8,
                    &lds[bufi][seg * 8]);
        } else {
            const int seg = (q - 2) * 512 + tid;
            const int row = seg >> 3;
            const int slot = (seg & 7) ^ (row & 7);
            gload16(Wt + (size_t)row * Ktot + (kt << 6) + slot * 8,
                    &lds[bufi][ASEG * 8 + seg * 8]);
        }
    };
    auto stage = [&](int kt, int bufi) {
#pragma unroll
        for (int q = 0; q < 6; ++q) stage1(kt, bufi, q);
    };

    f32x4 acc[4][4] = {};

    stage(0, 0);
    stage(1, 1);

    int buf = 0;
    for (int t = 0; t < nt; ++t) {
        const ushort* Ab = &lds[buf][0];
        const ushort* Bb = &lds[buf][ASEG * 8];
        if (t + 1 < nt) asm volatile("s_waitcnt vmcnt(6)" ::: "memory");
        else            asm volatile("s_waitcnt vmcnt(0)" ::: "memory");
        __builtin_amdgcn_sched_barrier(0);
        asm volatile("s_barrier" ::: "memory");
        __builtin_amdgcn_sched_barrier(0);

        int nbuf = buf + 2; if (nbuf >= 3) nbuf -= 3;
        const bool sb = (t + 2 < nt);

#pragma unroll
        for (int ks = 0; ks < 2; ++ks) {
            short8 bq[4], aq[4];
#pragma unroll
            for (int ni = 0; ni < 4; ++ni)
                bq[ni] = *(const short8*)(Bb + (wc * 64 + ni * 16 + l15) * 64 + ((((ks << 2) | lk) ^ axor) << 3));
#pragma unroll
            for (int mi = 0; mi < 4; ++mi)
                aq[mi] = *(const short8*)(Ab + (wr * 64 + mi * 16 + l15) * 64 + ((((ks << 2) | lk) ^ axor) << 3));
            if (sb) { stage1(t + 2, nbuf, 3 * ks); stage1(t + 2, nbuf, 3 * ks + 1); stage1(t + 2, nbuf, 3 * ks + 2); }
            asm volatile("s_waitcnt lgkmcnt(0)" ::: "memory");
            __builtin_amdgcn_sched_barrier(0);
            __builtin_amdgcn_s_setprio(1);
#pragma unroll
            for (int mi = 0; mi < 4; ++mi)
#pragma unroll
                for (int ni = 0; ni < 4; ++ni)
                    acc[mi][ni] = __builtin_amdgcn_mfma_f32_16x16x32_bf16(aq[mi], bq[ni], acc[mi][ni], 0, 0, 0);
            __builtin_amdgcn_s_setprio(0);
            __builtin_amdgcn_sched_barrier(0);
        }
        ++buf; if (buf == 3) buf = 0;
    }

#pragma unroll
    for (int mi = 0; mi < 4; ++mi)
#pragma unroll
        for (int ni = 0; ni < 4; ++ni)
#pragma unroll
            for (int jj = 0; jj < 4; ++jj) {
                const int r = m_base + wr * 64 + mi * 16 + 4 * lk + jj;
                const int n = n_base + wc * 64 + ni * 16 + l15;
                p.outB[(size_t)r * p.ldoB + n] = f2b(acc[mi][ni][jj]);
            }
}

// ---------------- g4: 4-wave, BM=128 BN=192, 2-deep ring, 2 blocks/CU ------------------
// haloA: A row addressing r -> r + 4*(r>>11) (halo'd input window GEMM).

struct G4P {
    const ushort* A;
    const ushort* W;
    int Ktot;
    int lda;
    ushort* outB; int ldoB;
    float*  outF; int ldoF;
    int act;
    int haloA;
};

__global__ __launch_bounds__(256, 2) void g4(G4P p) {
    constexpr int ASEG = 1024;   // 128 rows x 8
    constexpr int BSEG = 1536;   // 192 rows x 8
    __shared__ __align__(16) ushort lds[2][(ASEG + BSEG) * 8];   // 80 KB total

    const int tid = threadIdx.x;
    const int w = tid >> 6, lane = tid & 63;
    const int l15 = lane & 15, lk = lane >> 4;
    const int wr = w >> 1, wc = w & 1;
    const int axor = l15 & 7;
    const int m_base = blockIdx.x * 128;
    const int n_base = blockIdx.y * 192;
    const int nt = p.Ktot >> 6;
    const int abase = p.haloA ? (m_base + ((m_base >> 11) << 2)) : m_base;

    auto stage = [&](int kt, int bufi) {
        const int kk = kt << 6;
        ushort* Ab = &lds[bufi][0];
        ushort* Bb = &lds[bufi][ASEG * 8];
#pragma unroll
        for (int q = 0; q < 4; ++q) {
            const int seg = q * 256 + tid;
            const int row = seg >> 3;
            const int s = (seg & 7) ^ (row & 7);
            gload16(p.A + (size_t)(abase + row) * p.lda + kk + s * 8, Ab + seg * 8);
        }
#pragma unroll
        for (int q = 0; q < 6; ++q) {
            const int seg = q * 256 + tid;
            const int row = seg >> 3;
            const int s = (seg & 7) ^ (row & 7);
            gload16(p.W + (size_t)(n_base + row) * p.Ktot + kk + s * 8, Bb + seg * 8);
        }
    };

    f32x4 acc[4][6] = {};

    stage(0, 0);
    stage(1, 1);

    for (int t = 0; t < nt; ++t) {
        const int cur = t & 1;
        const ushort* Ab = &lds[cur][0];
        const ushort* Bb = &lds[cur][ASEG * 8];
        if (t + 1 < nt) asm volatile("s_waitcnt vmcnt(10)" ::: "memory");
        else            asm volatile("s_waitcnt vmcnt(0)" ::: "memory");
        __builtin_amdgcn_sched_barrier(0);
        asm volatile("s_barrier" ::: "memory");
        __builtin_amdgcn_sched_barrier(0);

        short8 af[4][2], bf[6][2];
#pragma unroll
        for (int mi = 0; mi < 4; ++mi)
#pragma unroll
            for (int ks = 0; ks < 2; ++ks)
                af[mi][ks] = *(const short8*)(Ab + (wr * 64 + mi * 16 + l15) * 64 + ((((ks << 2) | lk) ^ axor) << 3));
#pragma unroll
        for (int ni = 0; ni < 6; ++ni)
#pragma unroll
            for (int ks = 0; ks < 2; ++ks)
                bf[ni][ks] = *(const short8*)(Bb + (wc * 96 + ni * 16 + l15) * 64 + ((((ks << 2) | lk) ^ axor) << 3));
        asm volatile("s_waitcnt lgkmcnt(0)" ::: "memory");
        __builtin_amdgcn_sched_barrier(0);
        asm volatile("s_barrier" ::: "memory");
        __builtin_amdgcn_sched_barrier(0);
        if (t + 2 < nt) stage(t + 2, cur);
        __builtin_amdgcn_sched_barrier(0);
        __builtin_amdgcn_s_setprio(1);
#pragma unroll
        for (int mi = 0; mi < 4; ++mi)
#pragma unroll
            for (int ni = 0; ni < 6; ++ni) {
                acc[mi][ni] = __builtin_amdgcn_mfma_f32_16x16x32_bf16(af[mi][0], bf[ni][0], acc[mi][ni], 0, 0, 0);
                acc[mi][ni] = __builtin_amdgcn_mfma_f32_16x16x32_bf16(af[mi][1], bf[ni][1], acc[mi][ni], 0, 0, 0);
            }
        __builtin_amdgcn_s_setprio(0);
        __builtin_amdgcn_sched_barrier(0);
    }

#pragma unroll
    for (int mi = 0; mi < 4; ++mi)
#pragma unroll
        for (int ni = 0; ni < 6; ++ni)
#pragma unroll
            for (int jj = 0; jj < 4; ++jj) {
                const int r = m_base + wr * 64 + mi * 16 + 4 * lk + jj;
                const int n = n_base + wc * 96 + ni * 16 + l15;
                float v = acc[mi][ni][jj];
                if (p.act) v = fast_tanh(v);
                if (p.outF) p.outF[(size_t)r * p.ldoF + n] = v;
                if (p.outB) p.outB[(size_t)r * p.ldoB + n] = f2b(v);
            }
}

// ------- gemm_loc: location GEMM (BM=64, BN=128, 2-phase) + fused row-normalize --------

struct GLP {
    const ushort* A;      // h2 [MTOK][768]
    const ushort* Wt;     // enc_tr [128][768]
    float* outF;          // location f32 [MTOK][128]
    ushort* outH;         // halo'd location bf16 [B][SH][128]
    ushort* outN;         // normed bf16 [MTOK][128]
};

__global__ __launch_bounds__(256) void gemm_loc(GLP p) {
    __shared__ __align__(16) ushort As[64 * 64];
    __shared__ __align__(16) ushort Bs[128 * 64];
    __shared__ float rowss[64][2];
    const int tid = threadIdx.x;
    const int w = tid >> 6, lane = tid & 63;
    const int l15 = lane & 15, lk = lane >> 4;
    const int m_base = blockIdx.x * 64;
    const int wr = w >> 1, wc = w & 1;
    f32x4 acc[2][4] = {};
    const int srow = lane >> 3;
    const int scol = (lane & 7) * 8;

    for (int kt = 0; kt < 12; ++kt) {
        const int kk = kt << 6;
#pragma unroll
        for (int q = 0; q < 2; ++q) {
            const int r = w * 16 + q * 8;
            gload16(p.A + (size_t)(m_base + r + srow) * H_ + kk + scol, As + r * 64);
        }
#pragma unroll
        for (int q = 0; q < 4; ++q) {
            const int r = w * 32 + q * 8;
            gload16(p.Wt + (size_t)(r + srow) * H_ + kk + scol, Bs + r * 64);
        }
        __syncthreads();
#pragma unroll
        for (int ks = 0; ks < 2; ++ks) {
            short8 af[2], bfr[4];
#pragma unroll
            for (int i = 0; i < 2; ++i)
                af[i] = *(const short8*)(As + (wr * 32 + i * 16 + l15) * 64 + ks * 32 + 8 * lk);
#pragma unroll
            for (int j = 0; j < 4; ++j)
                bfr[j] = *(const short8*)(Bs + (wc * 64 + j * 16 + l15) * 64 + ks * 32 + 8 * lk);
#pragma unroll
            for (int i = 0; i < 2; ++i)
#pragma unroll
                for (int j = 0; j < 4; ++j)
                    acc[i][j] = __builtin_amdgcn_mfma_f32_16x16x32_bf16(af[i], bfr[j], acc[i][j], 0, 0, 0);
        }
        __syncthreads();
    }

#pragma unroll
    for (int i = 0; i < 2; ++i)
#pragma unroll
        for (int jj = 0; jj < 4; ++jj) {
            float s = acc[i][0][jj] * acc[i][0][jj] + acc[i][1][jj] * acc[i][1][jj]
                    + acc[i][2][jj] * acc[i][2][jj] + acc[i][3][jj] * acc[i][3][jj];
#pragma unroll
            for (int off = 1; off < 16; off <<= 1) s += __shfl_xor(s, off);
            if (l15 == 0) rowss[wr * 32 + i * 16 + 4 * lk + jj][wc] = s;
        }
    __syncthreads();

    const int bb4 = ((m_base >> 11) << 2) + 2;
#pragma unroll
    for (int i = 0; i < 2; ++i)
#pragma unroll
        for (int j = 0; j < 4; ++j)
#pragma unroll
            for (int jj = 0; jj < 4; ++jj) {
                const int lr = wr * 32 + i * 16 + 4 * lk + jj;
                const int r  = m_base + lr;
                const int n  = wc * 64 + j * 16 + l15;
                const float v = acc[i][j][jj];
                const float ss = rowss[lr][0] + rowss[lr][1];
                const float sc = 1.f / fmaxf(sqrtf(ss), 1e-8f);
                p.outF[(size_t)r * K_ + n] = v;
                p.outH[(size_t)(r + bb4) * K_ + n] = f2b(v);
                p.outN[(size_t)r * K_ + n] = f2b(v * sc);
            }
}

// ---------------- LayerNorm(conv_out + residual) -> bf16 ----------------

__global__ __launch_bounds__(192) void k_ln(const ushort* __restrict__ conv,
                                            const float* __restrict__ rep,
                                            const float* __restrict__ gw,
                                            const float* __restrict__ bw,
                                            ushort* __restrict__ out) {
    const int row = blockIdx.x;
    const int tid = threadIdx.x;
    const int h = tid * 4;
    const ushort4 cv = *(const ushort4*)(conv + (size_t)row * H_ + h);
    const float4  rv = *(const float4*)(rep + (size_t)row * H_ + h);
    float v[4] = { b2f(cv.x) + rv.x, b2f(cv.y) + rv.y, b2f(cv.z) + rv.z, b2f(cv.w) + rv.w };
    float s1 = v[0] + v[1] + v[2] + v[3];
    float s2 = v[0]*v[0] + v[1]*v[1] + v[2]*v[2] + v[3]*v[3];
#pragma unroll
    for (int off = 32; off; off >>= 1) { s1 += __shfl_xor(s1, off); s2 += __shfl_xor(s2, off); }
    __shared__ float sh[6];
    const int wid = tid >> 6, lane = tid & 63;
    if (lane == 0) { sh[wid] = s1; sh[3 + wid] = s2; }
    __syncthreads();
    s1 = sh[0] + sh[1] + sh[2];
    s2 = sh[3] + sh[4] + sh[5];
    const float mu  = s1 * (1.f / H_);
    const float var = s2 * (1.f / H_) - mu * mu;
    const float rs  = rsqrtf(var + 1e-5f);
    const float4 gv = *(const float4*)(gw + h);
    const float4 bv = *(const float4*)(bw + h);
    ushort4 o;
    o.x = f2b((v[0] - mu) * rs * gv.x + bv.x);
    o.y = f2b((v[1] - mu) * rs * gv.y + bv.y);
    o.z = f2b((v[2] - mu) * rs * gv.z + bv.z);
    o.w = f2b((v[3] - mu) * rs * gv.w + bv.w);
    *(ushort4*)(out + (size_t)row * H_ + h) = o;
}

// ---------------- banded cosine-sim + tags (fused; band-skip for compute) --------------

__global__ __launch_bounds__(256) void k_simtags(const ushort* __restrict__ normed,
                                                 const float* __restrict__ mask,
                                                 const int* __restrict__ Lp,
                                                 float* __restrict__ dis,
                                                 float* __restrict__ tags) {
    const int wid = threadIdx.x >> 6, lane = threadIdx.x & 63;
    const int l15 = lane & 15, lk = lane >> 4;
    const int b   = blockIdx.z;
    const int i0b = blockIdx.x * 64;
    const int i0  = i0b + wid * 16;
    const int j0  = blockIdx.y * 64;
    const int L   = *Lp;
    f32x4 acc[4] = {};
    if ((j0 + 63 >= i0b + 1) && (j0 <= i0b + 63 + L)) {
        const ushort* nb = normed + (size_t)b * S_ * K_;
#pragma unroll
        for (int kt = 0; kt < 4; ++kt) {
            const int kk = kt * 32;
            const short8 a = *(const short8*)(nb + (size_t)(i0 + l15) * K_ + kk + 8 * lk);
#pragma unroll
            for (int j = 0; j < 4; ++j) {
                const short8 bfr = *(const short8*)(nb + (size_t)(j0 + j * 16 + l15) * K_ + kk + 8 * lk);
                acc[j] = __builtin_amdgcn_mfma_f32_16x16x32_bf16(a, bfr, acc[j], 0, 0, 0);
            }
        }
    }
    const float* mb = mask + b * S_;
    float* dp = dis  + (size_t)b * S_ * S_;
    float* tp = tags + (size_t)b * S_ * S_;
#pragma unroll
    for (int j = 0; j < 4; ++j) {
#pragma unroll
        for (int jj = 0; jj < 4; ++jj) {
            const int i  = i0 + 4 * lk + jj;
            const int jc = j0 + j * 16 + l15;
            const int d  = jc - i;
            const bool band = (d >= 1 && d <= L);
            dp[(size_t)i * S_ + jc] = band ? acc[j][jj] : 0.f;
            tp[(size_t)i * S_ + jc] = band ? mb[i] * mb[jc] : 0.f;
        }
    }
}

// ---------------- host launch ----------------

extern "C" void kernel_launch(void* const* d_in, const int* in_sizes, int n_in,
                              void* d_out, int out_size, void* d_ws, size_t ws_size,
                              hipStream_t stream) {
    const float* rep  = (const float*)d_in[0];
    const float* mask = (const float*)d_in[1];
    const float* ew1  = (const float*)d_in[2];
    const float* ew3  = (const float*)d_in[3];
    const float* ew5  = (const float*)d_in[4];
    const float* lng  = (const float*)d_in[5];
    const float* lnb  = (const float*)d_in[6];
    const float* elin = (const float*)d_in[7];
    const float* etr  = (const float*)d_in[8];
    const float* dtr  = (const float*)d_in[9];
    const float* dw1  = (const float*)d_in[10];
    const float* dw3  = (const float*)d_in[11];
    const float* dw5  = (const float*)d_in[12];
    const float* dlin = (const float*)d_in[13];
    const float* olin = (const float*)d_in[14];

    float* out_loc = (float*)d_out;
    float* out_dis = out_loc + (size_t)B_ * S_ * K_;
    float* out_tag = out_dis + (size_t)B_ * S_ * S_;
    float* out_dec = out_tag + (size_t)B_ * S_ * S_;

    char* ws = (char*)d_ws;
    size_t off = 0;
    auto alloc = [&](size_t bytes) -> char* {
        char* p = ws + off;
        off += (bytes + 255) & ~(size_t)255;
        return p;
    };
    int*    Lp    = (int*)alloc(256);
    ushort* Xh    = (ushort*)alloc((size_t)B_ * SH_ * H_ * 2);   // halo'd rep
    ushort* bufLh = (ushort*)alloc((size_t)B_ * SH_ * K_ * 2);   // halo'd location
    ushort* wte1  = (ushort*)alloc((size_t)C_ * 768 * 2);
    ushort* wte3  = (ushort*)alloc((size_t)C_ * 2304 * 2);
    ushort* wte5  = (ushort*)alloc((size_t)C_ * 3840 * 2);
    ushort* wtd1  = (ushort*)alloc((size_t)C_ * 768 * 2);
    ushort* wtd3  = (ushort*)alloc((size_t)C_ * 2304 * 2);
    ushort* wtd5  = (ushort*)alloc((size_t)C_ * 3840 * 2);
    ushort* welin = (ushort*)alloc((size_t)H_ * H_ * 2);
    ushort* wetr  = (ushort*)alloc((size_t)K_ * H_ * 2);
    ushort* dtrT  = (ushort*)alloc((size_t)K_ * H_ * 2);         // dec_tr^T [128][768]
    ushort* wdlin = (ushort*)alloc((size_t)H_ * H_ * 2);
    ushort* wolin = (ushort*)alloc((size_t)H_ * H_ * 2);
    ushort* WcT   = (ushort*)alloc((size_t)640 * H_ * 2);        // window-form composite ^T
    ushort* Wz    = (ushort*)alloc((size_t)H_ * 640 * 2);        // Wdlin @ Wc  [768][640]
    ushort* bufB  = (ushort*)alloc((size_t)MTOK * H_ * 2);
    ushort* bufC  = (ushort*)alloc((size_t)MTOK * H_ * 2);
    ushort* bufD  = (ushort*)alloc((size_t)MTOK * H_ * 2);
    ushort* bufN  = (ushort*)alloc((size_t)MTOK * K_ * 2);
    if (ws_size < off) return;

    // 1. fused prep: maxlen + bufLh halo zero + halo'd rep + weight cvts + WcT zero
    PrepP pp;
    pp.mask = mask; pp.Lp = Lp; pp.lh = bufLh;
    pp.rep = rep; pp.xh = Xh;
    pp.e[0]  = { ew1,  wte1, 768 * C_,  768,  C_ };
    pp.e[1]  = { ew3,  wte3, 2304 * C_, 2304, C_ };
    pp.e[2]  = { ew5,  wte5, 3840 * C_, 3840, C_ };
    pp.e[3]  = { dw1,  wtd1, 768 * C_,  768,  C_ };
    pp.e[4]  = { dw3,  wtd3, 2304 * C_, 2304, C_ };
    pp.e[5]  = { dw5,  wtd5, 3840 * C_, 3840, C_ };
    pp.e[6]  = { elin, welin, H_ * H_, 0, 0 };
    pp.e[7]  = { etr,  wetr,  K_ * H_, 0, 0 };
    pp.e[8]  = { dlin, wdlin, H_ * H_, 0, 0 };
    pp.e[9]  = { olin, wolin, H_ * H_, 0, 0 };
    pp.e[10] = { dtr,  dtrT,  K_ * H_, 768, K_ };
    pp.e[11] = { nullptr, WcT, 640 * H_, -1, 0 };
    k_prep<<<dim3(2048, 13), 256, 0, stream>>>(pp);

    // 2. composite decoder conv weights -> WcT[640][768] (rows = window pos*128 + j)
    //    k1: chans 0-255, window pos 2; k3: chans 256-511, pos 1..3; k5: chans 512-767, pos 0..4
    {
        CompP cp; cp.dtrT = dtrT;
        cp.e[0] = { wtd1, 768,  0, WcT + 0,   768, 2 * 128 };
        for (int t = 0; t < 3; ++t)
            cp.e[1 + t] = { wtd3, 2304, t * 768, WcT + 256, 768, (1 + t) * 128 };
        for (int t = 0; t < 5; ++t)
            cp.e[4 + t] = { wtd5, 3840, t * 768, WcT + 512, 768, t * 128 };
        k_compw<<<dim3(2, 9), 256, 0, stream>>>(cp);
    }
    // 2b. Wz = wdlin @ Wc  -> [768][640]
    k_wz<<<dim3(H_ / 128, 640 / 128), 256, 0, stream>>>(wdlin, WcT, Wz);

    // 3. encoder convs -> bufB
    {
        G3P p{}; p.A = Xh; p.W0 = wte1; p.W1 = wte3; p.W2 = wte5;
        p.lda = H_; p.outB = bufB; p.ldoB = H_; p.nMtiles = MTOK / 128;
        g3<<<3 * (MTOK / 128), 512, 0, stream>>>(p);
    }
    // 4. LN(conv + rep) -> bufC
    k_ln<<<MTOK, 192, 0, stream>>>(bufB, rep, lng, lnb, bufC);
    // 5. h2 = tanh(h_ln @ enc_lin^T) -> bufD
    {
        G4P p{}; p.A = bufC; p.W = welin; p.Ktot = H_; p.lda = H_;
        p.outB = bufD; p.ldoB = H_; p.act = 1;
        g4<<<dim3(MTOK / 128, H_ / 192), 256, 0, stream>>>(p);
    }
    // 6. location -> out_loc + bufLh + bufN (fused normalize)
    {
        GLP p{ bufD, wetr, out_loc, bufLh, bufN };
        gemm_loc<<<MTOK / 64, 256, 0, stream>>>(p);
    }
    // 7. d2 = tanh( window(bufLh) @ Wz^T )  -> bufC   (dec conv + dec_lin fused)
    {
        G4P p{}; p.A = bufLh; p.W = Wz; p.Ktot = 640; p.lda = K_;
        p.outB = bufC; p.ldoB = H_; p.act = 1; p.haloA = 1;
        g4<<<dim3(MTOK / 128, H_ / 192), 256, 0, stream>>>(p);
    }
    // 8. decode_out = d2 @ out_lin^T -> out_dec
    {
        G4P p{}; p.A = bufC; p.W = wolin; p.Ktot = H_; p.lda = H_;
        p.outF = out_dec; p.ldoF = H_;
        g4<<<dim3(MTOK / 128, H_ / 192), 256, 0, stream>>>(p);
    }
    // 9. banded cosine sim + tags
    k_simtags<<<dim3(S_ / 64, S_ / 64, B_), 256, 0, stream>>>(bufN, mask, Lp, out_dis, out_tag);
}